// Round 3
// 1489.234 us; speedup vs baseline: 1.8483x; 1.8483x over previous
//
#include <hip/hip_runtime.h>

// ---------------------------------------------------------------------------
// GenesisV1: embed -> 256-step gated node recurrence -> LN -> vocab logits
//
// k_recur8: 8-way split of the 1024 gate|cand output columns -> 256 WGs on
// 256 CUs; per-wave weight slice (gate+cand n-tile = 32 KB = 128 VGPRs)
// loaded ONCE -> zero per-step weight traffic.
//
// Per-step h exchange among the 8 group-mates is FENCE-FREE: all exchange
// data moves via relaxed agent-scope u32 atomics (sc-bypass, performed at
// the LLC coherence point), counter barrier via relaxed agent atomic add +
// bounded spin. Correctness relies only on (a) sc-bypass semantics of
// agent-scope atomics and (b) __syncthreads() draining vmcnt(0) per wave
// before s_barrier. No __threadfence / wbl2 / inv anywhere -> no whole-L2
// invalidation per step, and no unbounded-hang failure mode (spin bound
// 4096 polls => worst case ~1 s total, surfaces as a failed check with
// counters instead of a dead container).
//
// Workspace discipline: xbuf + cnt alias the xfrag region (dead after
// k_xgemm); total footprint identical to the known-good baseline
// (64,225,280 B). cnt zeroed by k_zero between xgemm and recur8.
//
// MFMA fragment conventions:
//   A-frag: lane l holds A[m = l&15][k = (l>>4)*8 + j], j=0..7
//   B-frag: lane l holds B[k = (l>>4)*8 + j][n = l&15]
//   D:      lane l holds D[row = (l>>4)*4 + r][col = l&15]
// ---------------------------------------------------------------------------

#define NBATCH 8
#define SEQ    256
#define DM     512
#define VOCAB  32000
#define NNODES 64
#define MROWS  2048   // NBATCH*SEQ
#define KT     16     // DM/32 k-tiles

typedef __attribute__((ext_vector_type(8))) short s8v;  // 8 bf16 in 4 VGPRs
typedef __attribute__((ext_vector_type(4))) float f4v;

// ---- workspace layout (bytes) ----
#define OFF_XFRAG  0u                    // [128 mt][16 kt][64][8] bf16 : 2 MB
#define OFF_BPKTOP 2097152u              // [64 nt][16 kt][64][8] bf16 : 1 MB
#define OFF_BPKREC 3145728u              // same                       : 1 MB
#define OFF_WHPK   4194304u              // [2000 nt][16][64][8] bf16  : 32.77 MB
#define OFF_XGU    36962304u             // [2048][1024] f32           : 8 MB
#define OFF_PART   45350912u             // [8][4][256][512] f32       : 16.78 MB
#define OFF_NORM   62128128u             // [128 mt][16][64][8] bf16   : 2 MB
// aliases into the xfrag region (xfrag dead after k_xgemm):
#define OFF_XBUF   0u                    // [2][32 g][16 node][512 col] bf16 : 1 MB
#define OFF_CNT    1048576u              // 32 groups x 32 uints (128B stride)
// total 64,225,280 B == known-good baseline footprint

__device__ __forceinline__ short f2bf(float f) {
  unsigned u = __builtin_bit_cast(unsigned, f);
  u += 0x7fffu + ((u >> 16) & 1u);          // round-to-nearest-even
  return (short)(u >> 16);
}
__device__ __forceinline__ float fsig(float x) {
  float e = __builtin_amdgcn_exp2f(-1.4426950408889634f * x);
  return __builtin_amdgcn_rcpf(1.0f + e);
}
__device__ __forceinline__ float ftanh(float x) {
  float xc = fminf(fmaxf(x, -15.0f), 15.0f); // avoid inf/inf -> NaN
  float e = __builtin_amdgcn_exp2f(2.8853900817779268f * xc); // e^(2x)
  return (e - 1.0f) * __builtin_amdgcn_rcpf(e + 1.0f);
}

// ---- pack Wg/Wu (both [1024,512] f32) into top (x-part) and bottom (node-
// part) B-fragment tensors. nt 0..31 = gate cols, nt 32..63 = cand cols. ----
__global__ __launch_bounds__(256) void k_packw(const float* __restrict__ Wg,
                                               const float* __restrict__ Wu,
                                               short* __restrict__ top,
                                               short* __restrict__ rec) {
  int t = blockIdx.x * 256 + threadIdx.x;   // 131072 total
  int l = t & 63, kt = (t >> 6) & 15, nt = (t >> 10) & 31;
  int ub = (t >> 15) & 1, tb = (t >> 16) & 1;
  const float* src = ub ? Wu : Wg;
  int row0 = tb * 512 + kt * 32 + ((l >> 4) << 3);
  int col  = nt * 16 + (l & 15);
  short* dst = tb ? rec : top;
  int base = (((ub * 32 + nt) * KT + kt) * 64 + l) * 8;
#pragma unroll
  for (int j = 0; j < 8; ++j) dst[base + j] = f2bf(src[(row0 + j) * 512 + col]);
}

// ---- pack Wh [512,32000] f32 -> bf16 B-fragments ----
__global__ __launch_bounds__(256) void k_packwh(const float* __restrict__ Wh,
                                                short* __restrict__ whpk) {
  int t = blockIdx.x * 256 + threadIdx.x;   // 2,048,000 total
  int l = t & 63, kt = (t >> 6) & 15, nt = t >> 10;  // nt 0..1999
  int row0 = kt * 32 + ((l >> 4) << 3);
  int col  = nt * 16 + (l & 15);
  int base = ((nt * KT + kt) * 64 + l) * 8;
#pragma unroll
  for (int j = 0; j < 8; ++j) whpk[base + j] = f2bf(Wh[(row0 + j) * VOCAB + col]);
}

// ---- gather x = embedding[idx] -> bf16 A-fragments ----
__global__ __launch_bounds__(256) void k_gather(const int* __restrict__ idx,
                                                const float* __restrict__ emb,
                                                short* __restrict__ xfrag) {
  int t = blockIdx.x * 256 + threadIdx.x;   // 131072 total
  int l = t & 63, kt = (t >> 6) & 15, mt = t >> 10;  // mt 0..127
  int m = mt * 16 + (l & 15);
  int tok = idx[m];
  const float* e = emb + (long)tok * DM + kt * 32 + ((l >> 4) << 3);
  int base = ((mt * KT + kt) * 64 + l) * 8;
#pragma unroll
  for (int j = 0; j < 8; ++j) xfrag[base + j] = f2bf(e[j]);
}

// ---- Xgu = x @ [Wg_top|Wu_top] + [bg|bu] : [2048][1024] f32 ----
__global__ __launch_bounds__(256) void k_xgemm(const short* __restrict__ xfrag,
                                               const short* __restrict__ bpk,
                                               const float* __restrict__ bg,
                                               const float* __restrict__ bu,
                                               float* __restrict__ xgu) {
  int tid = threadIdx.x, l = tid & 63, w = tid >> 6;
  int mtb = blockIdx.x;            // 0..31 (4 mt each)
  int nt  = blockIdx.y * 4 + w;    // 0..63
  f4v acc[4];
#pragma unroll
  for (int mi = 0; mi < 4; ++mi) acc[mi] = 0;
  for (int kt = 0; kt < KT; ++kt) {
    s8v bf = *(const s8v*)(bpk + ((nt * KT + kt) * 64 + l) * 8);
#pragma unroll
    for (int mi = 0; mi < 4; ++mi) {
      s8v a = *(const s8v*)(xfrag + (((mtb * 4 + mi) * KT + kt) * 64 + l) * 8);
      acc[mi] = __builtin_amdgcn_mfma_f32_16x16x32_bf16(a, bf, acc[mi], 0, 0, 0);
    }
  }
  int n = nt * 16 + (l & 15);
  float bias = (n < 512) ? bg[n] : bu[n - 512];
#pragma unroll
  for (int mi = 0; mi < 4; ++mi)
#pragma unroll
    for (int r = 0; r < 4; ++r) {
      int m = (mtb * 4 + mi) * 16 + ((l >> 4) << 2) + r;
      xgu[m * 1024 + n] = acc[mi][r] + bias;
    }
}

// ---- zero the group sync counters (runs after k_xgemm frees the region) ----
__global__ __launch_bounds__(256) void k_zero(unsigned* __restrict__ cnt) {
  cnt[blockIdx.x * 256 + threadIdx.x] = 0u;   // 1024 uints
}

// ---- the recurrence, 8-way split: 256 WGs x 256 thr (4 waves).
// blockIdx = g*8 + oct; group g = (bat, nb) owns 16 nodes; WG computes
// gate/cand/h for cols [64*oct, 64*oct+64). Wave w: cols [64*oct+16w, +16).
// Weights for those cols live in 128 VGPRs for the whole kernel.
// Exchange buffer layout: [par][g][node 0..15][col 0..511] bf16 (u32 pairs).
__global__ __launch_bounds__(256, 1) void k_recur8(const short* __restrict__ bpk,
                                                   const float* __restrict__ xgu,
                                                   const float* __restrict__ mn,
                                                   float* __restrict__ part,
                                                   short* __restrict__ xbuf,
                                                   unsigned* __restrict__ cnt) {
  __shared__ short hfrag[KT * 64 * 8];        // 16 KB: A-frags of current h
  const int tid = threadIdx.x;
  const int l = tid & 63, w = tid >> 6;       // wave 0..3
  const int lm = l & 15, lq = l >> 4;
  const int g = blockIdx.x >> 3;              // group 0..31
  const int oct = blockIdx.x & 7;             // column octant 0..7
  const int bat = g >> 2, nb = g & 3;
  unsigned* cg = cnt + g * 32;                // 128B-strided counters

  // ---- load this wave's weight slice into registers (one-time) ----
  s8v wgr[KT], wur[KT];
  const int ng = 4 * oct + w;                 // gate n-tile 0..31
#pragma unroll
  for (int kt = 0; kt < KT; ++kt) {
    wgr[kt] = *(const s8v*)(bpk + ((ng * KT + kt) * 64 + l) * 8);
    wur[kt] = *(const s8v*)(bpk + (((32 + ng) * KT + kt) * 64 + l) * 8);
  }

  // ---- h(0) master for own cols (f32, D-layout) ----
  const int col = 64 * oct + 16 * w + lm;     // global col 0..511
  float hm[4];
#pragma unroll
  for (int r = 0; r < 4; ++r)
    hm[r] = mn[(nb * 16 + lq * 4 + r) * DM + col];

  // ---- build full h(0) A-frags in LDS from manifold_nodes ----
#pragma unroll
  for (int q = 0; q < 4; ++q) {
    int idx = q * 256 + tid;
    int kt = idx >> 6, ln = idx & 63;
    int node = nb * 16 + (ln & 15);
    const float* src = mn + node * DM + kt * 32 + ((ln >> 4) << 3);
    short tmp[8];
#pragma unroll
    for (int j = 0; j < 8; ++j) tmp[j] = f2bf(src[j]);
    *(s8v*)(hfrag + (kt * 64 + ln) * 8) = *(s8v*)tmp;
  }
  __syncthreads();

  float xg = xgu[(bat * SEQ) * 1024 + col];
  float xu = xgu[(bat * SEQ) * 1024 + 512 + col];

  for (int t = 0; t < SEQ; ++t) {
    f4v accg = 0, accu = 0;
#pragma unroll
    for (int kt = 0; kt < KT; ++kt) {
      s8v a = *(const s8v*)(hfrag + (kt * 64 + l) * 8);
      accg = __builtin_amdgcn_mfma_f32_16x16x32_bf16(a, wgr[kt], accg, 0, 0, 0);
      accu = __builtin_amdgcn_mfma_f32_16x16x32_bf16(a, wur[kt], accu, 0, 0, 0);
    }
    float ps = 0.0f;
#pragma unroll
    for (int r = 0; r < 4; ++r) {
      float gg = fsig(accg[r] + xg);
      float cc = ftanh(accu[r] + xu);
      float h = gg * cc + (1.0f - gg) * hm[r];
      hm[r] = h;
      ps += h;
    }
    // consensus partial: sum over this wave's 16 nodes for each own col
    ps += __shfl_xor(ps, 16);
    ps += __shfl_xor(ps, 32);
    if (l < 16)
      part[(((bat * 4 + nb) * SEQ + t) * DM) + col] = ps;

    if (t < SEQ - 1) {
      const int par = (t + 1) & 1;
      // scatter own h(t+1) slice as u32 bf16-pairs via agent-scope atomics
      // (sc-bypass -> LLC). Even-lm lane packs (col, col+1).
      unsigned* xw = (unsigned*)xbuf + (par * 32 + g) * 4096;
#pragma unroll
      for (int r = 0; r < 4; ++r) {
        float pr = __shfl_xor(hm[r], 1);      // all lanes execute the shuffle
        if (!(lm & 1)) {
          unsigned pv = (unsigned)(unsigned short)f2bf(hm[r])
                      | ((unsigned)(unsigned short)f2bf(pr) << 16);
          int node = lq * 4 + r;
          __hip_atomic_store(xw + ((node * 512 + col) >> 1), pv,
                             __ATOMIC_RELAXED, __HIP_MEMORY_SCOPE_AGENT);
        }
      }
      // prefetch next step's x-part preactivations (plain L2 loads; no L2
      // invalidation happens anymore, so xgu stays cached)
      const float* xrowN = xgu + (bat * SEQ + t + 1) * 1024;
      float xgN = xrowN[col], xuN = xrowN[512 + col];
      // barrier: each wave drains vmcnt(0) before s_barrier => all exchange
      // stores of this WG are LLC-visible before tid0 increments.
      __syncthreads();
      if (tid == 0) {
        __hip_atomic_fetch_add(cg, 1u, __ATOMIC_RELAXED,
                               __HIP_MEMORY_SCOPE_AGENT);
        const unsigned tgt = 8u * (unsigned)(t + 1);
        int spins = 0;
        while (__hip_atomic_load(cg, __ATOMIC_RELAXED,
                                 __HIP_MEMORY_SCOPE_AGENT) < tgt) {
          __builtin_amdgcn_s_sleep(2);
          if (++spins > 4096) break;          // bounded: no GPU hang, ever
        }
      }
      __syncthreads();
      // reload full h(t+1) (all 8 octants) via agent-scope atomic loads
      // (sc-bypass -> always fresh from LLC), repack into A-frags in LDS
      const unsigned* xr = (const unsigned*)xbuf + (par * 32 + g) * 4096;
#pragma unroll
      for (int q = 0; q < 4; ++q) {
        int idx = q * 256 + tid;
        int kt = idx >> 6, ln = idx & 63;
        int o32 = ((ln & 15) * 512 + kt * 32 + ((ln >> 4) << 3)) >> 1;
        unsigned d0 = __hip_atomic_load(xr + o32 + 0, __ATOMIC_RELAXED,
                                        __HIP_MEMORY_SCOPE_AGENT);
        unsigned d1 = __hip_atomic_load(xr + o32 + 1, __ATOMIC_RELAXED,
                                        __HIP_MEMORY_SCOPE_AGENT);
        unsigned d2 = __hip_atomic_load(xr + o32 + 2, __ATOMIC_RELAXED,
                                        __HIP_MEMORY_SCOPE_AGENT);
        unsigned d3 = __hip_atomic_load(xr + o32 + 3, __ATOMIC_RELAXED,
                                        __HIP_MEMORY_SCOPE_AGENT);
        union { unsigned u[4]; s8v v; } c;
        c.u[0] = d0; c.u[1] = d1; c.u[2] = d2; c.u[3] = d3;
        *(s8v*)(hfrag + (kt * 64 + ln) * 8) = c.v;
      }
      xg = xgN;
      xu = xuN;
      __syncthreads();
    }
  }
}

// ---- consensus = sum(partials)/64 -> LayerNorm -> bf16 A-fragments ----
__global__ __launch_bounds__(1024) void k_ln(const float* __restrict__ part,
                                             const float* __restrict__ lnw,
                                             const float* __restrict__ lnb,
                                             short* __restrict__ nfrag) {
  __shared__ short tile[16 * DM];           // 16 KB
  int tid = threadIdx.x, w = tid >> 6, l = tid & 63;
  int bI = blockIdx.x;                      // 0..127  (16 rows each)
  int m = bI * 16 + w;
  int bat = m >> 8, t = m & 255;
  const float* p0 = part + ((bat * 4) * SEQ + t) * DM;
  float vx[8];
#pragma unroll
  for (int j = 0; j < 8; ++j) {
    int d = l * 8 + j;
    vx[j] = (p0[d] + p0[d + 131072] + p0[d + 262144] + p0[d + 393216]) * (1.0f / 64.0f);
  }
  float s = 0;
#pragma unroll
  for (int j = 0; j < 8; ++j) s += vx[j];
  for (int msk = 1; msk < 64; msk <<= 1) s += __shfl_xor(s, msk);
  float mean = s * (1.0f / 512.0f);
  float q = 0;
#pragma unroll
  for (int j = 0; j < 8; ++j) { float d = vx[j] - mean; q += d * d; }
  for (int msk = 1; msk < 64; msk <<= 1) q += __shfl_xor(q, msk);
  float rs = rsqrtf(q * (1.0f / 512.0f) + 1e-5f);
#pragma unroll
  for (int j = 0; j < 8; ++j) {
    int d = l * 8 + j;
    tile[w * DM + d] = f2bf((vx[j] - mean) * rs * lnw[d] + lnb[d]);
  }
  __syncthreads();
  // re-emit in A-fragment order: thread tid -> (kt = w, lane l)
  s8v val = *(const s8v*)(&tile[(l & 15) * DM + w * 32 + ((l >> 4) << 3)]);
  *(s8v*)(nfrag + ((bI * KT + w) * 64 + l) * 8) = val;
}

// ---- logits = normed @ Wh + bh : [2048][32000] f32 out ----
__global__ __launch_bounds__(512) void k_logits(const short* __restrict__ nfrag,
                                                const short* __restrict__ whpk,
                                                const float* __restrict__ bh,
                                                float* __restrict__ out) {
  int tid = threadIdx.x, l = tid & 63, w = tid >> 6;  // 8 waves
  int wm = w >> 2, wn = w & 3;
  int ntb = blockIdx.x;   // 0..124 (256 cols each)
  int mtb = blockIdx.y;   // 0..7   (256 rows each)
  f4v acc[8][4];
#pragma unroll
  for (int mi = 0; mi < 8; ++mi)
#pragma unroll
    for (int ni = 0; ni < 4; ++ni) acc[mi][ni] = 0;
  for (int kt = 0; kt < KT; ++kt) {
    s8v bf[4];
#pragma unroll
    for (int ni = 0; ni < 4; ++ni)
      bf[ni] = *(const s8v*)(whpk + (((ntb * 16 + wn * 4 + ni) * KT + kt) * 64 + l) * 8);
#pragma unroll
    for (int mi = 0; mi < 8; ++mi) {
      s8v a = *(const s8v*)(nfrag + (((mtb * 16 + wm * 8 + mi) * KT + kt) * 64 + l) * 8);
#pragma unroll
      for (int ni = 0; ni < 4; ++ni)
        acc[mi][ni] = __builtin_amdgcn_mfma_f32_16x16x32_bf16(a, bf[ni], acc[mi][ni], 0, 0, 0);
    }
  }
#pragma unroll
  for (int ni = 0; ni < 4; ++ni) {
    int n = (ntb * 16 + wn * 4 + ni) * 16 + (l & 15);
    float bias = bh[n];
#pragma unroll
    for (int mi = 0; mi < 8; ++mi) {
      int mrow = (mtb * 16 + wm * 8 + mi) * 16 + ((l >> 4) << 2);
#pragma unroll
      for (int r = 0; r < 4; ++r)
        out[(long)(mrow + r) * VOCAB + n] = acc[mi][ni][r] + bias;
    }
  }
}

extern "C" void kernel_launch(void* const* d_in, const int* in_sizes, int n_in,
                              void* d_out, int out_size, void* d_ws, size_t ws_size,
                              hipStream_t stream) {
  (void)in_sizes; (void)n_in; (void)out_size; (void)ws_size;
  const int*   idx = (const int*)  d_in[0];
  const float* emb = (const float*)d_in[1];
  const float* mn  = (const float*)d_in[2];
  const float* Wg  = (const float*)d_in[3];
  const float* bg  = (const float*)d_in[4];
  const float* Wu  = (const float*)d_in[5];
  const float* bu  = (const float*)d_in[6];
  const float* lnw = (const float*)d_in[7];
  const float* lnb = (const float*)d_in[8];
  const float* Wh  = (const float*)d_in[9];
  const float* bh  = (const float*)d_in[10];
  float* out = (float*)d_out;
  char* ws = (char*)d_ws;
  short* xfrag  = (short*)(ws + OFF_XFRAG);
  short* bpktop = (short*)(ws + OFF_BPKTOP);
  short* bpkrec = (short*)(ws + OFF_BPKREC);
  short* whpk   = (short*)(ws + OFF_WHPK);
  float* xgu    = (float*)(ws + OFF_XGU);
  float* part   = (float*)(ws + OFF_PART);
  short* nfrag  = (short*)(ws + OFF_NORM);
  short* xbuf   = (short*)(ws + OFF_XBUF);   // aliases xfrag (dead post-xgemm)
  unsigned* cnt = (unsigned*)(ws + OFF_CNT); // aliases xfrag (dead post-xgemm)

  k_packw <<<dim3(512),      dim3(256),  0, stream>>>(Wg, Wu, bpktop, bpkrec);
  k_packwh<<<dim3(8000),     dim3(256),  0, stream>>>(Wh, whpk);
  k_gather<<<dim3(512),      dim3(256),  0, stream>>>(idx, emb, xfrag);
  k_xgemm <<<dim3(32, 16),   dim3(256),  0, stream>>>(xfrag, bpktop, bg, bu, xgu);
  k_zero  <<<dim3(4),        dim3(256),  0, stream>>>(cnt);
  k_recur8<<<dim3(256),      dim3(256),  0, stream>>>(bpkrec, xgu, mn, part, xbuf, cnt);
  k_ln    <<<dim3(128),      dim3(1024), 0, stream>>>(part, lnw, lnb, nfrag);
  k_logits<<<dim3(125, 8),   dim3(512),  0, stream>>>(nfrag, whpk, bh, out);
}